// Round 17
// baseline (150.704 us; speedup 1.0000x reference)
//
#include <hip/hip_runtime.h>
#include <cmath>

// SSIM + L1 image similarity loss, MI355X (gfx950).
// es, ta: fp32 [16,3,512,512]. Output: out[0]=l1_loss, out[1]=ssim_loss.
//
// R17 = R16 (78us: 4-channel u/v rotation, packed v2f, batched staging,
// VGPR 40 no-spill) with ONE change: TILE_H 32 -> 48 (12 rows/wave).
//  - horizontal redundancy 2.25x -> 1.83x: per-pixel main VALU -14%,
//    LDS bytes/pixel -19%.
//  - LDS 35.3KB -> 4 blocks/CU -> 16 waves/CU (from 24): affordable since
//    VALUBusy=75% means work, not latency, dominates now.
//  - accumulators 48 regs, live ~80 -> fits cap 128 (R11's 12-row failure
//    was the 5-channel version, 20 regs heavier).
//  - y-guard on last stripe (512 = 10*48 + 32).

typedef float v2f __attribute__((ext_vector_type(2)));

constexpr int TILE_W = 64;
constexpr int TILE_H = 48;
constexpr int HALO = 5;
constexpr int WIN  = 11;
constexpr int ROWS_PER_WAVE = TILE_H / 4;            // 12
constexpr int STREAM_ROWS = ROWS_PER_WAVE + WIN - 1; // 22
constexpr int LH   = TILE_H + 2 * HALO;  // 58 staged rows
constexpr int LW   = TILE_W + 2 * HALO;  // 74 staged cols
constexpr int LSTR = 76;                 // LDS row stride (v2f units)
constexpr int IMG  = 512;
constexpr int TOTAL = LH * LW;           // 4292 staged elements
constexpr int NIT = (TOTAL + 255) / 256; // 17 stage iterations
constexpr float C1C = 0.01f * 0.01f;
constexpr float C2C = 0.03f * 0.03f;

struct Wnd { float g[WIN]; };

__global__ __launch_bounds__(256, 2) void ssim_main(
    const float* __restrict__ es, const float* __restrict__ ta,
    float2* __restrict__ partials, Wnd w)
{
    __shared__ v2f sS[LH * LSTR];
    __shared__ float2 red[4];

    const int tid = threadIdx.x;
    const int tx0 = blockIdx.x * TILE_W;
    const int ty0 = blockIdx.y * TILE_H;
    const int img = blockIdx.z;
    const float* pe = es + (size_t)img * (IMG * IMG);
    const float* pt = ta + (size_t)img * (IMG * IMG);

    // ---- stage, phase A: issue all loads (clamped addr, no branches) ----
    float se[NIT], st_[NIT];
    #pragma unroll
    for (int it = 0; it < NIT; ++it) {
        int i = it * 256 + tid;
        int r = i / LW, c = i - r * LW;
        int gy = ty0 - HALO + r;
        int gx = tx0 - HALO + c;
        int cy = min(max(gy, 0), IMG - 1);
        int cx = min(max(gx, 0), IMG - 1);
        int off = cy * IMG + cx;
        if (i < TOTAL) {                 // divergent only at it==16
            se[it]  = pe[off];
            st_[it] = pt[off];
        }
    }

    // ---- stage, phase B: zero-pad select + (u,v) transform + LDS write ----
    #pragma unroll
    for (int it = 0; it < NIT; ++it) {
        int i = it * 256 + tid;
        if (i < TOTAL) {
            int r = i / LW, c = i - r * LW;
            int gy = ty0 - HALO + r;
            int gx = tx0 - HALO + c;
            bool valid = ((unsigned)gy < (unsigned)IMG) &&
                         ((unsigned)gx < (unsigned)IMG);
            float m = valid ? 1.f : 0.f;
            float e = se[it] * m, t = st_[it] * m;
            sS[r * LSTR + c] = (v2f){e + t, e - t};   // (u, v)
        }
    }
    __syncthreads();

    const int wv = tid >> 6;   // wave id 0..3 -> 12-row segment
    const int ln = tid & 63;   // lane -> column
    const int rbase = wv * ROWS_PER_WAVE;
    const v2f* rp = &sS[rbase * LSTR + ln];

    v2f am[ROWS_PER_WAVE];     // (mu_u, mu_v) accumulators
    v2f aq[ROWS_PER_WAVE];     // (E[u^2], E[v^2]) accumulators
    #pragma unroll
    for (int o = 0; o < ROWS_PER_WAVE; ++o) {
        am[o] = (v2f){0.f, 0.f}; aq[o] = (v2f){0.f, 0.f};
    }

    #pragma unroll
    for (int rr = 0; rr < STREAM_ROWS; ++rr) {
        // horizontal 11-tap of {(u,v), (u^2,v^2)} for streamed row rr
        v2f hm = {0.f, 0.f};
        v2f hq = {0.f, 0.f};
        #pragma unroll
        for (int k = 0; k < WIN; ++k) {
            v2f uv = rp[rr * LSTR + k];     // ds_read_b64, imm offset
            float gk = w.g[k];
            v2f g2 = {gk, gk};
            v2f gu = g2 * uv;               // v_pk_mul_f32
            hm += gu;                       // v_pk_add_f32
            hq += gu * uv;                  // v_pk_fma_f32
        }

        // vertical scatter: streamed row rr feeds output rows rr-10..rr
        #pragma unroll
        for (int k = 0; k < WIN; ++k) {
            int o = rr - k;
            if (o >= 0 && o < ROWS_PER_WAVE) {
                float gk = w.g[k];
                v2f g2 = {gk, gk};
                am[o] += g2 * hm;           // v_pk_fma_f32
                aq[o] += g2 * hq;           // v_pk_fma_f32
            }
        }
    }

    // ---- epilogue: ssim per pixel + L1, then reduce ----
    float ssim_s = 0.f, l1_s = 0.f;
    #pragma unroll
    for (int o = 0; o < ROWS_PER_WAVE; ++o) {
        if (ty0 + rbase + o < IMG) {       // skip padded rows (last stripe)
            float mu_u = am[o].x, mu_v = am[o].y;
            float mu_u2 = mu_u * mu_u, mu_v2 = mu_v * mu_v;
            float var_u = aq[o].x - mu_u2;
            float var_v = aq[o].y - mu_v2;
            float m12_2 = (mu_u2 - mu_v2) * 0.5f;   // 2*mu1*mu2
            float msum  = (mu_u2 + mu_v2) * 0.5f;   // mu1^2+mu2^2
            float cov2  = (var_u - var_v) * 0.5f;   // 2*sigma12
            float vsum  = (var_u + var_v) * 0.5f;   // sigma1^2+sigma2^2
            float num = (m12_2 + C1C) * (cov2 + C2C);
            float den = (msum + C1C) * (vsum + C2C);
            ssim_s += num * __builtin_amdgcn_rcpf(den);

            v2f c = rp[(o + HALO) * LSTR + HALO];   // center (u,v)
            l1_s += fabsf(c.y);                     // |e-t| = |v|
        }
    }

    // ---- block reduce: wave shfl -> LDS[4] -> thread 0 stores partial ----
    #pragma unroll
    for (int off = 32; off >= 1; off >>= 1) {
        ssim_s += __shfl_xor(ssim_s, off, 64);
        l1_s   += __shfl_xor(l1_s, off, 64);
    }
    if (ln == 0) red[wv] = make_float2(ssim_s, l1_s);
    __syncthreads();
    if (tid == 0) {
        float2 r0 = red[0], r1 = red[1], r2 = red[2], r3 = red[3];
        float2 p = make_float2(r0.x + r1.x + r2.x + r3.x,
                               r0.y + r1.y + r2.y + r3.y);
        int bid = (blockIdx.z * gridDim.y + blockIdx.y) * gridDim.x + blockIdx.x;
        partials[bid] = p;
    }
}

__global__ __launch_bounds__(256) void ssim_reduce(
    const float2* __restrict__ partials, int n, float* __restrict__ out)
{
    __shared__ float2 red[4];
    const int tid = threadIdx.x;
    float ssim_s = 0.f, l1_s = 0.f;
    for (int i = tid; i < n; i += 256) {
        float2 p = partials[i];
        ssim_s += p.x;
        l1_s   += p.y;
    }
    #pragma unroll
    for (int off = 32; off >= 1; off >>= 1) {
        ssim_s += __shfl_xor(ssim_s, off, 64);
        l1_s   += __shfl_xor(l1_s, off, 64);
    }
    if ((tid & 63) == 0) red[tid >> 6] = make_float2(ssim_s, l1_s);
    __syncthreads();
    if (tid == 0) {
        float s = red[0].x + red[1].x + red[2].x + red[3].x;
        float l = red[0].y + red[1].y + red[2].y + red[3].y;
        const float N = 16.f * 3.f * 512.f * 512.f;
        out[0] = 0.15f * (l / N);
        out[1] = 0.85f * 0.5f * (1.f - s / N);
    }
}

extern "C" void kernel_launch(void* const* d_in, const int* in_sizes, int n_in,
                              void* d_out, int out_size, void* d_ws, size_t ws_size,
                              hipStream_t stream)
{
    const float* es = (const float*)d_in[0];
    const float* ta = (const float*)d_in[1];
    float* out = (float*)d_out;
    float2* partials = (float2*)d_ws;

    Wnd w;
    double gd[WIN], sum = 0.0;
    for (int i = 0; i < WIN; ++i) {
        double x = (double)(i - WIN / 2);
        gd[i] = std::exp(-(x * x) / (2.0 * 1.5 * 1.5));
        sum += gd[i];
    }
    for (int i = 0; i < WIN; ++i) w.g[i] = (float)(gd[i] / sum);

    const int nimg = in_sizes[0] / (IMG * IMG);  // 16*3 = 48
    dim3 grid(IMG / TILE_W, (IMG + TILE_H - 1) / TILE_H, nimg);  // 8 x 11 x 48
    const int nblocks = grid.x * grid.y * grid.z;                // 4224
    ssim_main<<<grid, 256, 0, stream>>>(es, ta, partials, w);
    ssim_reduce<<<1, 256, 0, stream>>>(partials, nblocks, out);
}